// Round 8
// baseline (93.863 us; speedup 1.0000x reference)
//
#include <hip/hip_runtime.h>
#include <cstdint>
#include <cstddef>

// ---------------------------------------------------------------------------
// MultiHeadExternalAttention, algebraically collapsed:
//   logits = x @ Wk   (Wk[e,hm] = sum_d W_in[e,h*128+d]*W_mk[d,m]) + bk
//   attn   = softmax_n(logits); attn /= (sum_m attn + 1e-9)
//   out    = attn @ Wv (Wv[hm,e] = sum_d W_mv[m,d]*W_out[h*128+d,e]) + bv
// B=32 N=1024 E=512 H=16 M=16 HM=256 ROWS=32768
// Round 8: fix gemm_a staging loop bound (i<8, 4096 cells — round 7's i<16
// wrote 2x the LDS tile -> OOB abort). Structure otherwise identical:
//  gemm_a: 64-row block, A panel staged seq -> swizzled LDS, B frags from L2.
//  gemm_b: p_prep fused in-register (exp/inv/head-norm via shfl), A from L3.
// ---------------------------------------------------------------------------

typedef unsigned short u16;
typedef unsigned int u32;
typedef short s16x8 __attribute__((ext_vector_type(8)));
typedef float f32x4 __attribute__((ext_vector_type(4)));

// workspace layout (bytes)
constexpr size_t OFF_WKT  = 1u << 20;                 // u16 [256][512]  (256 KiB)
constexpr size_t OFF_WVT  = OFF_WKT + (1u << 18);     // u16 [512][256]  (256 KiB)
constexpr size_t OFF_BK   = OFF_WVT + (1u << 18);     // f32 [256]
constexpr size_t OFF_BV   = OFF_BK + 4096;            // f32 [512]
constexpr size_t OFF_INV  = OFF_BV + 4096;            // f32 [32][256]
constexpr size_t OFF_CP   = 2u << 20;                 // f32 [512][256] colsum partials
constexpr size_t OFF_LOG  = 4u << 20;                 // u16 [32768][256] (16 MiB)
constexpr size_t OFF_WVP  = 40u << 20;                // f32 [128][512][16] (4 MiB)
constexpr size_t OFF_BVP  = 45u << 20;                // f32 [128][512] (256 KiB)

__device__ __forceinline__ float bf2f(u16 v) {
  union { u32 u; float f; } c; c.u = ((u32)v) << 16; return c.f;
}
__device__ __forceinline__ u16 f2bf(float f) {
  union { float f; u32 u; } c; c.f = f;
  u32 u = c.u;
  u += 0x7fffu + ((u >> 16) & 1u);
  return (u16)(u >> 16);
}
// packed RNE f32x2 -> bf16x2 (single HW op; no builtin on gfx950)
__device__ __forceinline__ u32 cvt2(float lo, float hi) {
  u32 r;
  asm("v_cvt_pk_bf16_f32 %0, %1, %2" : "=v"(r) : "v"(lo), "v"(hi));
  return r;
}
__device__ __forceinline__ uint4 pack_bf8(float4 lo, float4 hi) {
  return make_uint4(cvt2(lo.x, lo.y), cvt2(lo.z, lo.w),
                    cvt2(hi.x, hi.y), cvt2(hi.z, hi.w));
}
__device__ __forceinline__ s16x8 as_s16x8(uint4 v) {
  union { uint4 u; s16x8 s; } c; c.u = v; return c.s;
}

__device__ __forceinline__ void mfma_bf16(f32x4& acc, s16x8 a, s16x8 b) {
  asm volatile("v_mfma_f32_16x16x32_bf16 %0, %1, %2, %0"
               : "+v"(acc) : "v"(a), "v"(b));
}

// ---------------------------------------------------------------------------
// WkT[hm][e] = sum_d W_in[e, h*128+d] * W_mk[d, m]   (stored transposed, bf16)
__global__ void prep_wkt(const float* __restrict__ wi, const float* __restrict__ wm,
                         u16* __restrict__ wkT) {
  const int gid = blockIdx.x * 256 + threadIdx.x;
  const int hm = gid & 255, e = gid >> 8;
  const int h = hm >> 4, m = hm & 15;
  float acc = 0.f;
  for (int d = 0; d < 128; d++)
    acc += wi[e * 2048 + h * 128 + d] * wm[d * 16 + m];
  wkT[hm * 512 + e] = f2bf(acc);
}

// wvt partial: block = (h, dc); 16 d's per chunk; coalesced W_out rows.
__global__ __launch_bounds__(256) void wvt_part(const float* __restrict__ mv,
                                                const float* __restrict__ b_mv,
                                                const float* __restrict__ wo,
                                                float* __restrict__ wvp,
                                                float* __restrict__ bvp) {
  __shared__ float wmv_l[16][16];
  __shared__ float bmv_l[16];
  const int blk = blockIdx.x;        // 0..127
  const int h = blk >> 3, dc = blk & 7;
  const int t = threadIdx.x;         // 256
  {
    const int m = t >> 4, dd = t & 15;
    wmv_l[m][dd] = mv[m * 128 + dc * 16 + dd];
    if (t < 16) bmv_l[t] = b_mv[dc * 16 + t];
  }
  __syncthreads();
  float acc0[16], acc1[16];
  float bv0 = 0.f, bv1 = 0.f;
#pragma unroll
  for (int m = 0; m < 16; m++) { acc0[m] = 0.f; acc1[m] = 0.f; }
#pragma unroll
  for (int dd = 0; dd < 16; dd++) {
    const float w0 = wo[(size_t)(h * 128 + dc * 16 + dd) * 512 + t];
    const float w1 = wo[(size_t)(h * 128 + dc * 16 + dd) * 512 + 256 + t];
#pragma unroll
    for (int m = 0; m < 16; m++) {
      const float c = wmv_l[m][dd];
      acc0[m] += c * w0;
      acc1[m] += c * w1;
    }
    bv0 += bmv_l[dd] * w0;
    bv1 += bmv_l[dd] * w1;
  }
  float* w0p = wvp + ((size_t)blk * 512 + t) * 16;
  float* w1p = wvp + ((size_t)blk * 512 + 256 + t) * 16;
#pragma unroll
  for (int m = 0; m < 16; m++) { w0p[m] = acc0[m]; w1p[m] = acc1[m]; }
  bvp[(size_t)blk * 512 + t] = bv0;
  bvp[(size_t)blk * 512 + 256 + t] = bv1;
}

// wvT[e][hm] = f2bf(sum_dc wvp); bv[e] = b_out[e] + sum_blk bvp
__global__ __launch_bounds__(256) void wvt_fin(const float* __restrict__ wvp,
                                               const float* __restrict__ bvp,
                                               const float* __restrict__ b_out,
                                               u16* __restrict__ wvT,
                                               float* __restrict__ bv) {
  const int e = blockIdx.x;   // 512
  const int t = threadIdx.x;  // 256 = hm
  const int h = t >> 4, m = t & 15;
  float s = 0.f;
#pragma unroll
  for (int dc = 0; dc < 8; dc++)
    s += wvp[((size_t)(h * 8 + dc) * 512 + e) * 16 + m];
  wvT[(size_t)e * 256 + t] = f2bf(s);
  if (t < 64) {
    float b = bvp[(size_t)t * 512 + e] + bvp[(size_t)(t + 64) * 512 + e];
#pragma unroll
    for (int mask = 32; mask >= 1; mask >>= 1) b += __shfl_xor(b, mask);
    if (t == 0) bv[e] = b_out[e] + b;
  }
}

// bk[hm] = b_mk[m] + sum_d b_in[h*128+d]*W_mk[d,m]
__global__ void prep_bk(const float* __restrict__ b_in, const float* __restrict__ wm,
                        const float* __restrict__ b_mk, float* __restrict__ bk) {
  const int t = threadIdx.x;
  const int h = t >> 4, m = t & 15;
  float acc = b_mk[m];
  for (int d = 0; d < 128; d++) acc += b_in[h * 128 + d] * wm[d * 16 + m];
  bk[t] = acc;
}

// ---------------------------------------------------------------------------
// GEMM A: logits[32768,256] = x[32768,512] @ Wk + bk (bf16) + colsum partials.
// Grid 512 blocks of 64 rows x 256 cols, 8 waves (wave = 64 rows x 32 cols).
// A: 64x512 fp32 panel read block-linear SEQUENTIAL -> cvt -> 64KB LDS,
//    cells [row][kg^(row&7)] of 8 bf16 (T2 XOR swizzle).
// B: wkT (256KB, L2-resident) per-lane global frags, depth-2 prefetch.
// No K-loop barriers.
__global__ __launch_bounds__(512, 4) void gemm_a(const float* __restrict__ x,
                                                 const u16* __restrict__ wkT,
                                                 const float* __restrict__ bk,
                                                 u16* __restrict__ logits,
                                                 float* __restrict__ cpart) {
  __shared__ u16 As[32768];  // 64 rows * 64 kg * 8 bf16 = 64 KiB
  const int t = threadIdx.x;
  const int l = t & 63, w = t >> 6;
  const int lrow = l & 15, lkg = l >> 4;
  const int gRow0 = blockIdx.x << 6;

  // stage A: fully sequential reads. 4096 cells (64 rows x 64 kg, 8 floats
  // each) over 512 threads = 8 iterations. (Round 7 bug: i<16 doubled this.)
  const float4* x4 = (const float4*)(x + (size_t)gRow0 * 512);
#pragma unroll
  for (int i = 0; i < 8; i++) {
    const int j = i * 512 + t;          // cell id: row = j>>6, kg = j&63
    const int row = j >> 6, kg = j & 63;
    const float4 f0 = x4[j * 2];
    const float4 f1 = x4[j * 2 + 1];
    *(uint4*)&As[((row << 6) + (kg ^ (row & 7))) * 8] = pack_bf8(f0, f1);
  }
  __syncthreads();

  f32x4 acc[4][2];
#pragma unroll
  for (int i = 0; i < 4; i++)
#pragma unroll
    for (int n = 0; n < 2; n++) acc[i][n] = f32x4{0.f, 0.f, 0.f, 0.f};

  // B frags: col = w*32 + n*16 + lrow, k-slice lkg*8 + kc*32
  const u16* bBase = wkT + (size_t)(w * 32 + lrow) * 512 + lkg * 8;
  uint4 bPre[2][2];
  bPre[0][0] = *(const uint4*)(bBase);
  bPre[0][1] = *(const uint4*)(bBase + 16 * 512);
  bPre[1][0] = *(const uint4*)(bBase + 32);
  bPre[1][1] = *(const uint4*)(bBase + 16 * 512 + 32);

#pragma unroll
  for (int kc = 0; kc < 16; ++kc) {
    const int d = kc & 1;
    s16x8 af[4];
#pragma unroll
    for (int i = 0; i < 4; i++)
      af[i] = *(const s16x8*)
          &As[(((i * 16 + lrow) << 6) + ((kc * 4 + lkg) ^ (lrow & 7))) * 8];
    const s16x8 b0 = as_s16x8(bPre[d][0]);
    const s16x8 b1 = as_s16x8(bPre[d][1]);
    if (kc + 2 < 16) {
      bPre[d][0] = *(const uint4*)(bBase + (kc + 2) * 32);
      bPre[d][1] = *(const uint4*)(bBase + 16 * 512 + (kc + 2) * 32);
    }
#pragma unroll
    for (int i = 0; i < 4; i++) {
      mfma_bf16(acc[i][0], af[i], b0);
      mfma_bf16(acc[i][1], af[i], b1);
    }
  }

  asm volatile("s_nop 7\n\ts_nop 7");
  const int crow = lkg * 4;  // C/D: row = (l>>4)*4 + j, col = l&15
  float esum[2];
#pragma unroll
  for (int n = 0; n < 2; n++) {
    const int col = w * 32 + n * 16 + lrow;
    const float bias = bk[col];
    float es = 0.f;
#pragma unroll
    for (int i = 0; i < 4; i++) {
      const int row0 = gRow0 + i * 16 + crow;
#pragma unroll
      for (int j = 0; j < 4; j++) {
        const u16 q = f2bf(acc[i][n][j] + bias);
        logits[(size_t)(row0 + j) * 256 + col] = q;
        es += __expf(bf2f(q));
      }
    }
    esum[n] = es;
  }
  // reduce over the 4 lkg groups (lanes l, l^16, l^32 share col)
#pragma unroll
  for (int n = 0; n < 2; n++) {
    esum[n] += __shfl_xor(esum[n], 16);
    esum[n] += __shfl_xor(esum[n], 32);
  }
  if (l < 16) {
    cpart[(size_t)blockIdx.x * 256 + w * 32 + l] = esum[0];
    cpart[(size_t)blockIdx.x * 256 + w * 32 + 16 + l] = esum[1];
  }
}

// inv[b][hm] = 1 / sum over the batch's 16 row-block partials
__global__ void colsum_fin(const float* __restrict__ cpart, float* __restrict__ inv) {
  const int b = blockIdx.x, hm = threadIdx.x;
  float s = 0.f;
#pragma unroll
  for (int k = 0; k < 16; k++) s += cpart[(size_t)(b * 16 + k) * 256 + hm];
  inv[b * 256 + hm] = 1.0f / s;
}

// ---------------------------------------------------------------------------
// GEMM B (p_prep fused): out[32768,512] = P @ Wv + bv, P computed in-register:
//   E = exp(logit); A' = E*inv; P = A' / (sum_m A' + 1e-9)   (head-local sum
//   = lane-sum8 + shfl_xor(16): lanes lkg0/1 = head kc*2, lkg2/3 = kc*2+1).
// Grid 512 blocks of 64 rows x 512 cols, 8 waves (wave = 64 rows x 64 cols).
// A-frags from L3-resident logits; B (wvT, L2) frags; depth-2 prefetch.
__global__ __launch_bounds__(512, 2) void gemm_b(const u16* __restrict__ lg,
                                                 const float* __restrict__ inv,
                                                 const u16* __restrict__ wvT,
                                                 const float* __restrict__ bvv,
                                                 float* __restrict__ out) {
  __shared__ float invl[256];
  const int t = threadIdx.x;
  const int l = t & 63, w = t >> 6;
  const int lrow = l & 15, lkg = l >> 4;
  const int gRow0 = blockIdx.x << 6;
  const int bIdx = blockIdx.x >> 4;
  if (t < 256) invl[t] = inv[bIdx * 256 + t];
  __syncthreads();

  f32x4 acc[4][4];
#pragma unroll
  for (int i = 0; i < 4; i++)
#pragma unroll
    for (int n = 0; n < 4; n++) acc[i][n] = f32x4{0.f, 0.f, 0.f, 0.f};

  const u16* aBase = lg + (size_t)gRow0 * 256 + lkg * 8;   // + (i*16+lrow)*256 + kc*32
  const u16* bBase = wvT + (size_t)(w * 64 + lrow) * 256 + lkg * 8;  // + n*4096 + kc*32

  uint4 aPre[2][4], bPre[2][4];
#pragma unroll
  for (int i = 0; i < 4; i++) {
    aPre[0][i] = *(const uint4*)(aBase + (i * 16 + lrow) * 256);
    aPre[1][i] = *(const uint4*)(aBase + (i * 16 + lrow) * 256 + 32);
    bPre[0][i] = *(const uint4*)(bBase + i * 4096);
    bPre[1][i] = *(const uint4*)(bBase + i * 4096 + 32);
  }

#pragma unroll
  for (int kc = 0; kc < 8; ++kc) {
    const int d = kc & 1;
    const float4 iv0 = *(const float4*)&invl[kc * 32 + lkg * 8];
    const float4 iv1 = *(const float4*)&invl[kc * 32 + lkg * 8 + 4];
    s16x8 pa[4];
#pragma unroll
    for (int i = 0; i < 4; i++) {
      const uint4 q = aPre[d][i];
      float e0 = __expf(bf2f((u16)(q.x & 0xffffu))) * iv0.x;
      float e1 = __expf(bf2f((u16)(q.x >> 16)))     * iv0.y;
      float e2 = __expf(bf2f((u16)(q.y & 0xffffu))) * iv0.z;
      float e3 = __expf(bf2f((u16)(q.y >> 16)))     * iv0.w;
      float e4 = __expf(bf2f((u16)(q.z & 0xffffu))) * iv1.x;
      float e5 = __expf(bf2f((u16)(q.z >> 16)))     * iv1.y;
      float e6 = __expf(bf2f((u16)(q.w & 0xffffu))) * iv1.z;
      float e7 = __expf(bf2f((u16)(q.w >> 16)))     * iv1.w;
      float s = ((e0 + e1) + (e2 + e3)) + ((e4 + e5) + (e6 + e7));
      s += __shfl_xor(s, 16);   // pair lkg0<->1 (head kc*2), lkg2<->3 (kc*2+1)
      const float rs = 1.0f / (s + 1e-9f);
      pa[i] = as_s16x8(make_uint4(cvt2(e0 * rs, e1 * rs), cvt2(e2 * rs, e3 * rs),
                                  cvt2(e4 * rs, e5 * rs), cvt2(e6 * rs, e7 * rs)));
    }
    s16x8 bf[4];
#pragma unroll
    for (int n = 0; n < 4; n++) bf[n] = as_s16x8(bPre[d][n]);
    if (kc + 2 < 8) {
#pragma unroll
      for (int i = 0; i < 4; i++) {
        aPre[d][i] = *(const uint4*)(aBase + (i * 16 + lrow) * 256 + (kc + 2) * 32);
        bPre[d][i] = *(const uint4*)(bBase + i * 4096 + (kc + 2) * 32);
      }
    }
#pragma unroll
    for (int i = 0; i < 4; i++)
#pragma unroll
      for (int n = 0; n < 4; n++) mfma_bf16(acc[i][n], pa[i], bf[n]);
  }

  asm volatile("s_nop 7\n\ts_nop 7");
  const int crow = lkg * 4;
#pragma unroll
  for (int n = 0; n < 4; n++) {
    const int col = w * 64 + n * 16 + lrow;
    const float bias = bvv[col];
#pragma unroll
    for (int i = 0; i < 4; i++) {
      const int row0 = gRow0 + i * 16 + crow;
#pragma unroll
      for (int j = 0; j < 4; j++)
        out[(size_t)(row0 + j) * 512 + col] = acc[i][n][j] + bias;
    }
  }
}

// ---------------------------------------------------------------------------
extern "C" void kernel_launch(void* const* d_in, const int* in_sizes, int n_in,
                              void* d_out, int out_size, void* d_ws, size_t ws_size,
                              hipStream_t stream) {
  (void)in_sizes; (void)n_in; (void)out_size; (void)ws_size;
  const float* x     = (const float*)d_in[0];
  const float* W_in  = (const float*)d_in[1];
  const float* b_in  = (const float*)d_in[2];
  const float* W_mk  = (const float*)d_in[3];
  const float* b_mk  = (const float*)d_in[4];
  const float* W_mv  = (const float*)d_in[5];
  const float* b_mv  = (const float*)d_in[6];
  const float* W_out = (const float*)d_in[7];
  const float* b_out = (const float*)d_in[8];

  char* ws = (char*)d_ws;
  u16*   wkT  = (u16*)(ws + OFF_WKT);
  u16*   wvT  = (u16*)(ws + OFF_WVT);
  float* bk   = (float*)(ws + OFF_BK);
  float* bv   = (float*)(ws + OFF_BV);
  float* inv  = (float*)(ws + OFF_INV);
  float* cp   = (float*)(ws + OFF_CP);
  u16*   lg   = (u16*)(ws + OFF_LOG);
  float* wvp  = (float*)(ws + OFF_WVP);
  float* bvp  = (float*)(ws + OFF_BVP);
  float* outp = (float*)d_out;

  prep_wkt<<<512, 256, 0, stream>>>(W_in, W_mk, wkT);
  wvt_part<<<128, 256, 0, stream>>>(W_mv, b_mv, W_out, wvp, bvp);
  wvt_fin<<<512, 256, 0, stream>>>(wvp, bvp, b_out, wvT, bv);
  prep_bk<<<1, 256, 0, stream>>>(b_in, W_mk, b_mk, bk);
  gemm_a<<<512, 512, 0, stream>>>(x, wkT, bk, lg, cp);
  colsum_fin<<<32, 256, 0, stream>>>(cp, inv);
  gemm_b<<<512, 512, 0, stream>>>(lg, inv, wvT, bv, outp);
}

// Round 9
// 86.838 us; speedup vs baseline: 1.0809x; 1.0809x over previous
//
#include <hip/hip_runtime.h>
#include <cstdint>
#include <cstddef>

// ---------------------------------------------------------------------------
// MultiHeadExternalAttention, algebraically collapsed:
//   logits = x @ Wk   (Wk[e,hm] = sum_d W_in[e,h*128+d]*W_mk[d,m]) + bk
//   attn   = softmax_n(logits); attn /= (sum_m attn + 1e-9)
//   out    = attn @ Wv (Wv[hm,e] = sum_d W_mv[m,d]*W_out[h*128+d,e]) + bv
// B=32 N=1024 E=512 H=16 M=16 HM=256 ROWS=32768
// Round 9: gemm_b softmax deduplicated -> cooperative LDS P-tile phase
// (was 8x redundant per wave, VALUBusy 34%); gemm_a staging split
// issue/consume for guaranteed outstanding loads.
// ---------------------------------------------------------------------------

typedef unsigned short u16;
typedef unsigned int u32;
typedef short s16x8 __attribute__((ext_vector_type(8)));
typedef float f32x4 __attribute__((ext_vector_type(4)));

// workspace layout (bytes)
constexpr size_t OFF_WKT  = 1u << 20;                 // u16 [256][512]  (256 KiB)
constexpr size_t OFF_WVT  = OFF_WKT + (1u << 18);     // u16 [512][256]  (256 KiB)
constexpr size_t OFF_BK   = OFF_WVT + (1u << 18);     // f32 [256]
constexpr size_t OFF_BV   = OFF_BK + 4096;            // f32 [512]
constexpr size_t OFF_INV  = OFF_BV + 4096;            // f32 [32][256]
constexpr size_t OFF_CP   = 2u << 20;                 // f32 [512][256] colsum partials
constexpr size_t OFF_LOG  = 4u << 20;                 // u16 [32768][256] (16 MiB)
constexpr size_t OFF_WVP  = 40u << 20;                // f32 [128][512][16] (4 MiB)
constexpr size_t OFF_BVP  = 45u << 20;                // f32 [128][512] (256 KiB)

__device__ __forceinline__ float bf2f(u16 v) {
  union { u32 u; float f; } c; c.u = ((u32)v) << 16; return c.f;
}
__device__ __forceinline__ u16 f2bf(float f) {
  union { float f; u32 u; } c; c.f = f;
  u32 u = c.u;
  u += 0x7fffu + ((u >> 16) & 1u);
  return (u16)(u >> 16);
}
// packed RNE f32x2 -> bf16x2 (single HW op; no builtin on gfx950)
__device__ __forceinline__ u32 cvt2(float lo, float hi) {
  u32 r;
  asm("v_cvt_pk_bf16_f32 %0, %1, %2" : "=v"(r) : "v"(lo), "v"(hi));
  return r;
}
__device__ __forceinline__ uint4 pack_bf8(float4 lo, float4 hi) {
  return make_uint4(cvt2(lo.x, lo.y), cvt2(lo.z, lo.w),
                    cvt2(hi.x, hi.y), cvt2(hi.z, hi.w));
}
__device__ __forceinline__ s16x8 as_s16x8(uint4 v) {
  union { uint4 u; s16x8 s; } c; c.u = v; return c.s;
}

__device__ __forceinline__ void mfma_bf16(f32x4& acc, s16x8 a, s16x8 b) {
  asm volatile("v_mfma_f32_16x16x32_bf16 %0, %1, %2, %0"
               : "+v"(acc) : "v"(a), "v"(b));
}

// ---------------------------------------------------------------------------
// WkT[hm][e] = sum_d W_in[e, h*128+d] * W_mk[d, m]   (stored transposed, bf16)
__global__ void prep_wkt(const float* __restrict__ wi, const float* __restrict__ wm,
                         u16* __restrict__ wkT) {
  const int gid = blockIdx.x * 256 + threadIdx.x;
  const int hm = gid & 255, e = gid >> 8;
  const int h = hm >> 4, m = hm & 15;
  float acc = 0.f;
  for (int d = 0; d < 128; d++)
    acc += wi[e * 2048 + h * 128 + d] * wm[d * 16 + m];
  wkT[hm * 512 + e] = f2bf(acc);
}

// wvt partial: block = (h, dc); 16 d's per chunk; coalesced W_out rows.
__global__ __launch_bounds__(256) void wvt_part(const float* __restrict__ mv,
                                                const float* __restrict__ b_mv,
                                                const float* __restrict__ wo,
                                                float* __restrict__ wvp,
                                                float* __restrict__ bvp) {
  __shared__ float wmv_l[16][16];
  __shared__ float bmv_l[16];
  const int blk = blockIdx.x;        // 0..127
  const int h = blk >> 3, dc = blk & 7;
  const int t = threadIdx.x;         // 256
  {
    const int m = t >> 4, dd = t & 15;
    wmv_l[m][dd] = mv[m * 128 + dc * 16 + dd];
    if (t < 16) bmv_l[t] = b_mv[dc * 16 + t];
  }
  __syncthreads();
  float acc0[16], acc1[16];
  float bv0 = 0.f, bv1 = 0.f;
#pragma unroll
  for (int m = 0; m < 16; m++) { acc0[m] = 0.f; acc1[m] = 0.f; }
#pragma unroll
  for (int dd = 0; dd < 16; dd++) {
    const float w0 = wo[(size_t)(h * 128 + dc * 16 + dd) * 512 + t];
    const float w1 = wo[(size_t)(h * 128 + dc * 16 + dd) * 512 + 256 + t];
#pragma unroll
    for (int m = 0; m < 16; m++) {
      const float c = wmv_l[m][dd];
      acc0[m] += c * w0;
      acc1[m] += c * w1;
    }
    bv0 += bmv_l[dd] * w0;
    bv1 += bmv_l[dd] * w1;
  }
  float* w0p = wvp + ((size_t)blk * 512 + t) * 16;
  float* w1p = wvp + ((size_t)blk * 512 + 256 + t) * 16;
#pragma unroll
  for (int m = 0; m < 16; m++) { w0p[m] = acc0[m]; w1p[m] = acc1[m]; }
  bvp[(size_t)blk * 512 + t] = bv0;
  bvp[(size_t)blk * 512 + 256 + t] = bv1;
}

// wvT[e][hm] = f2bf(sum_dc wvp); bv[e] = b_out[e] + sum_blk bvp
__global__ __launch_bounds__(256) void wvt_fin(const float* __restrict__ wvp,
                                               const float* __restrict__ bvp,
                                               const float* __restrict__ b_out,
                                               u16* __restrict__ wvT,
                                               float* __restrict__ bv) {
  const int e = blockIdx.x;   // 512
  const int t = threadIdx.x;  // 256 = hm
  const int h = t >> 4, m = t & 15;
  float s = 0.f;
#pragma unroll
  for (int dc = 0; dc < 8; dc++)
    s += wvp[((size_t)(h * 8 + dc) * 512 + e) * 16 + m];
  wvT[(size_t)e * 256 + t] = f2bf(s);
  if (t < 64) {
    float b = bvp[(size_t)t * 512 + e] + bvp[(size_t)(t + 64) * 512 + e];
#pragma unroll
    for (int mask = 32; mask >= 1; mask >>= 1) b += __shfl_xor(b, mask);
    if (t == 0) bv[e] = b_out[e] + b;
  }
}

// bk[hm] = b_mk[m] + sum_d b_in[h*128+d]*W_mk[d,m]
__global__ void prep_bk(const float* __restrict__ b_in, const float* __restrict__ wm,
                        const float* __restrict__ b_mk, float* __restrict__ bk) {
  const int t = threadIdx.x;
  const int h = t >> 4, m = t & 15;
  float acc = b_mk[m];
  for (int d = 0; d < 128; d++) acc += b_in[h * 128 + d] * wm[d * 16 + m];
  bk[t] = acc;
}

// ---------------------------------------------------------------------------
// GEMM A: logits[32768,256] = x[32768,512] @ Wk + bk (bf16) + colsum partials.
// Grid 512 blocks of 64 rows x 256 cols, 8 waves (wave = 64 rows x 32 cols).
// A: 64x512 fp32 panel read block-linear SEQUENTIAL, loads all issued before
//    packing (explicit issue/consume split) -> cvt -> 64KB swizzled LDS.
// B: wkT (256KB, L2-resident) per-lane global frags, depth-2 prefetch.
// No K-loop barriers.
__global__ __launch_bounds__(512, 4) void gemm_a(const float* __restrict__ x,
                                                 const u16* __restrict__ wkT,
                                                 const float* __restrict__ bk,
                                                 u16* __restrict__ logits,
                                                 float* __restrict__ cpart) {
  __shared__ u16 As[32768];  // 64 rows * 64 kg * 8 bf16 = 64 KiB
  const int t = threadIdx.x;
  const int l = t & 63, w = t >> 6;
  const int lrow = l & 15, lkg = l >> 4;
  const int gRow0 = blockIdx.x << 6;

  // stage A: 4096 cells over 512 threads = 8 cells (16 float4 loads) each.
  // Issue ALL loads first, then pack+write (keeps 16 loads in flight).
  const float4* x4 = (const float4*)(x + (size_t)gRow0 * 512);
  float4 fr[16];
#pragma unroll
  for (int i = 0; i < 8; i++) {
    const int j = i * 512 + t;
    fr[i * 2]     = x4[j * 2];
    fr[i * 2 + 1] = x4[j * 2 + 1];
  }
#pragma unroll
  for (int i = 0; i < 8; i++) {
    const int j = i * 512 + t;          // cell id: row = j>>6, kg = j&63
    const int row = j >> 6, kg = j & 63;
    *(uint4*)&As[((row << 6) + (kg ^ (row & 7))) * 8] =
        pack_bf8(fr[i * 2], fr[i * 2 + 1]);
  }
  __syncthreads();

  f32x4 acc[4][2];
#pragma unroll
  for (int i = 0; i < 4; i++)
#pragma unroll
    for (int n = 0; n < 2; n++) acc[i][n] = f32x4{0.f, 0.f, 0.f, 0.f};

  // B frags: col = w*32 + n*16 + lrow, k-slice lkg*8 + kc*32
  const u16* bBase = wkT + (size_t)(w * 32 + lrow) * 512 + lkg * 8;
  uint4 bPre[2][2];
  bPre[0][0] = *(const uint4*)(bBase);
  bPre[0][1] = *(const uint4*)(bBase + 16 * 512);
  bPre[1][0] = *(const uint4*)(bBase + 32);
  bPre[1][1] = *(const uint4*)(bBase + 16 * 512 + 32);

#pragma unroll
  for (int kc = 0; kc < 16; ++kc) {
    const int d = kc & 1;
    s16x8 af[4];
#pragma unroll
    for (int i = 0; i < 4; i++)
      af[i] = *(const s16x8*)
          &As[(((i * 16 + lrow) << 6) + ((kc * 4 + lkg) ^ (lrow & 7))) * 8];
    const s16x8 b0 = as_s16x8(bPre[d][0]);
    const s16x8 b1 = as_s16x8(bPre[d][1]);
    if (kc + 2 < 16) {
      bPre[d][0] = *(const uint4*)(bBase + (kc + 2) * 32);
      bPre[d][1] = *(const uint4*)(bBase + 16 * 512 + (kc + 2) * 32);
    }
#pragma unroll
    for (int i = 0; i < 4; i++) {
      mfma_bf16(acc[i][0], af[i], b0);
      mfma_bf16(acc[i][1], af[i], b1);
    }
  }

  asm volatile("s_nop 7\n\ts_nop 7");
  const int crow = lkg * 4;  // C/D: row = (l>>4)*4 + j, col = l&15
  float esum[2];
#pragma unroll
  for (int n = 0; n < 2; n++) {
    const int col = w * 32 + n * 16 + lrow;
    const float bias = bk[col];
    float es = 0.f;
#pragma unroll
    for (int i = 0; i < 4; i++) {
      const int row0 = gRow0 + i * 16 + crow;
#pragma unroll
      for (int j = 0; j < 4; j++) {
        const u16 q = f2bf(acc[i][n][j] + bias);
        logits[(size_t)(row0 + j) * 256 + col] = q;
        es += __expf(bf2f(q));
      }
    }
    esum[n] = es;
  }
  // reduce over the 4 lkg groups (lanes l, l^16, l^32 share col)
#pragma unroll
  for (int n = 0; n < 2; n++) {
    esum[n] += __shfl_xor(esum[n], 16);
    esum[n] += __shfl_xor(esum[n], 32);
  }
  if (l < 16) {
    cpart[(size_t)blockIdx.x * 256 + w * 32 + l] = esum[0];
    cpart[(size_t)blockIdx.x * 256 + w * 32 + 16 + l] = esum[1];
  }
}

// inv[b][hm] = 1 / sum over the batch's 16 row-block partials
__global__ void colsum_fin(const float* __restrict__ cpart, float* __restrict__ inv) {
  const int b = blockIdx.x, hm = threadIdx.x;
  float s = 0.f;
#pragma unroll
  for (int k = 0; k < 16; k++) s += cpart[(size_t)(b * 16 + k) * 256 + hm];
  inv[b * 256 + hm] = 1.0f / s;
}

// ---------------------------------------------------------------------------
// GEMM B: out[32768,512] = P @ Wv + bv (fp32 out).
// Grid (2 colblk, 512 rowblk); block = 64 rows x 256 cols, 8 waves
// (wave = 64 rows x 32 cols, acc[4][2]).
// Phase 1 (cooperative, once per block): P[64][256] -> 32 KiB swizzled LDS.
//   thread = (row r=t>>3, chunk ko=t&7 of 32 hm = 2 heads); head-denominators
//   are thread-local sums (no shfl).
// Phase 2: pure MFMA loop; A-frags from LDS, B (wvT, L2) depth-2 prefetch;
// no K-loop barriers.
__global__ __launch_bounds__(512, 4) void gemm_b(const u16* __restrict__ lg,
                                                 const float* __restrict__ inv,
                                                 const u16* __restrict__ wvT,
                                                 const float* __restrict__ bvv,
                                                 float* __restrict__ out) {
  __shared__ u16 Ps[16384];  // 64 rows * 32 kg * 8 bf16 = 32 KiB
  const int t = threadIdx.x;
  const int l = t & 63, w = t >> 6;
  const int lrow = l & 15, lkg = l >> 4;
  const int gCol0 = blockIdx.x << 8;
  const int gRow0 = blockIdx.y << 6;
  const int bIdx = blockIdx.y >> 4;   // 16 row-blocks per batch

  // ---- phase 1: P tile ----
  {
    const int r = t >> 3, ko = t & 7;
    const u16* src = lg + (size_t)(gRow0 + r) * 256 + ko * 32;
    const float* ivp = inv + bIdx * 256 + ko * 32;
    uint4 q[4];
    q[0] = ((const uint4*)src)[0];
    q[1] = ((const uint4*)src)[1];
    q[2] = ((const uint4*)src)[2];
    q[3] = ((const uint4*)src)[3];
    float4 iva[8];
#pragma unroll
    for (int c = 0; c < 8; c++) iva[c] = ((const float4*)ivp)[c];
    float e[32];
#pragma unroll
    for (int c = 0; c < 4; c++) {
      const u32 w0 = q[c].x, w1 = q[c].y, w2 = q[c].z, w3 = q[c].w;
      const float4 ia = iva[c * 2], ib = iva[c * 2 + 1];
      e[c * 8 + 0] = __expf(bf2f((u16)(w0 & 0xffffu))) * ia.x;
      e[c * 8 + 1] = __expf(bf2f((u16)(w0 >> 16)))     * ia.y;
      e[c * 8 + 2] = __expf(bf2f((u16)(w1 & 0xffffu))) * ia.z;
      e[c * 8 + 3] = __expf(bf2f((u16)(w1 >> 16)))     * ia.w;
      e[c * 8 + 4] = __expf(bf2f((u16)(w2 & 0xffffu))) * ib.x;
      e[c * 8 + 5] = __expf(bf2f((u16)(w2 >> 16)))     * ib.y;
      e[c * 8 + 6] = __expf(bf2f((u16)(w3 & 0xffffu))) * ib.z;
      e[c * 8 + 7] = __expf(bf2f((u16)(w3 >> 16)))     * ib.w;
    }
    float s0 = 0.f, s1 = 0.f;
#pragma unroll
    for (int p = 0; p < 16; p++) { s0 += e[p]; s1 += e[16 + p]; }
    const float r0 = 1.0f / (s0 + 1e-9f), r1 = 1.0f / (s1 + 1e-9f);
#pragma unroll
    for (int c = 0; c < 4; c++) {
      const float rs = (c < 2) ? r0 : r1;
      const uint4 cell = make_uint4(
          cvt2(e[c * 8 + 0] * rs, e[c * 8 + 1] * rs),
          cvt2(e[c * 8 + 2] * rs, e[c * 8 + 3] * rs),
          cvt2(e[c * 8 + 4] * rs, e[c * 8 + 5] * rs),
          cvt2(e[c * 8 + 6] * rs, e[c * 8 + 7] * rs));
      const int kg = ko * 4 + c;
      *(uint4*)&Ps[((r << 5) + (kg ^ (r & 7))) * 8] = cell;
    }
  }
  __syncthreads();

  // ---- phase 2: GEMM ----
  f32x4 acc[4][2];
#pragma unroll
  for (int i = 0; i < 4; i++)
#pragma unroll
    for (int n = 0; n < 2; n++) acc[i][n] = f32x4{0.f, 0.f, 0.f, 0.f};

  const u16* bBase = wvT + (size_t)(gCol0 + w * 32 + lrow) * 256 + lkg * 8;
  uint4 bPre[2][2];
  bPre[0][0] = *(const uint4*)(bBase);
  bPre[0][1] = *(const uint4*)(bBase + 16 * 256);
  bPre[1][0] = *(const uint4*)(bBase + 32);
  bPre[1][1] = *(const uint4*)(bBase + 16 * 256 + 32);

#pragma unroll
  for (int kc = 0; kc < 8; ++kc) {
    const int d = kc & 1;
    s16x8 af[4];
#pragma unroll
    for (int i = 0; i < 4; i++)
      af[i] = *(const s16x8*)
          &Ps[(((i * 16 + lrow) << 5) + ((kc * 4 + lkg) ^ (lrow & 7))) * 8];
    const s16x8 b0 = as_s16x8(bPre[d][0]);
    const s16x8 b1 = as_s16x8(bPre[d][1]);
    if (kc + 2 < 8) {
      bPre[d][0] = *(const uint4*)(bBase + (kc + 2) * 32);
      bPre[d][1] = *(const uint4*)(bBase + 16 * 256 + (kc + 2) * 32);
    }
#pragma unroll
    for (int i = 0; i < 4; i++) {
      mfma_bf16(acc[i][0], af[i], b0);
      mfma_bf16(acc[i][1], af[i], b1);
    }
  }

  asm volatile("s_nop 7\n\ts_nop 7");
  const int crow = lkg * 4;
#pragma unroll
  for (int n = 0; n < 2; n++) {
    const int col = gCol0 + w * 32 + n * 16 + lrow;
    const float bias = bvv[col];
#pragma unroll
    for (int i = 0; i < 4; i++) {
      const int row0 = gRow0 + i * 16 + crow;
#pragma unroll
      for (int j = 0; j < 4; j++)
        out[(size_t)(row0 + j) * 512 + col] = acc[i][n][j] + bias;
    }
  }
}

// ---------------------------------------------------------------------------
extern "C" void kernel_launch(void* const* d_in, const int* in_sizes, int n_in,
                              void* d_out, int out_size, void* d_ws, size_t ws_size,
                              hipStream_t stream) {
  (void)in_sizes; (void)n_in; (void)out_size; (void)ws_size;
  const float* x     = (const float*)d_in[0];
  const float* W_in  = (const float*)d_in[1];
  const float* b_in  = (const float*)d_in[2];
  const float* W_mk  = (const float*)d_in[3];
  const float* b_mk  = (const float*)d_in[4];
  const float* W_mv  = (const float*)d_in[5];
  const float* b_mv  = (const float*)d_in[6];
  const float* W_out = (const float*)d_in[7];
  const float* b_out = (const float*)d_in[8];

  char* ws = (char*)d_ws;
  u16*   wkT  = (u16*)(ws + OFF_WKT);
  u16*   wvT  = (u16*)(ws + OFF_WVT);
  float* bk   = (float*)(ws + OFF_BK);
  float* bv   = (float*)(ws + OFF_BV);
  float* inv  = (float*)(ws + OFF_INV);
  float* cp   = (float*)(ws + OFF_CP);
  u16*   lg   = (u16*)(ws + OFF_LOG);
  float* wvp  = (float*)(ws + OFF_WVP);
  float* bvp  = (float*)(ws + OFF_BVP);
  float* outp = (float*)d_out;

  prep_wkt<<<512, 256, 0, stream>>>(W_in, W_mk, wkT);
  wvt_part<<<128, 256, 0, stream>>>(W_mv, b_mv, W_out, wvp, bvp);
  wvt_fin<<<512, 256, 0, stream>>>(wvp, bvp, b_out, wvT, bv);
  prep_bk<<<1, 256, 0, stream>>>(b_in, W_mk, b_mk, bk);
  gemm_a<<<512, 512, 0, stream>>>(x, wkT, bk, lg, cp);
  colsum_fin<<<32, 256, 0, stream>>>(cp, inv);
  gemm_b<<<dim3(2, 512), 512, 0, stream>>>(lg, inv, wvT, bv, outp);
}

// Round 10
// 84.824 us; speedup vs baseline: 1.1066x; 1.0237x over previous
//
#include <hip/hip_runtime.h>
#include <cstdint>
#include <cstddef>

// ---------------------------------------------------------------------------
// MultiHeadExternalAttention, algebraically collapsed:
//   logits = x @ Wk   (Wk[e,hm] = sum_d W_in[e,h*128+d]*W_mk[d,m]) + bk
//   attn   = softmax_n(logits); attn /= (sum_m attn + 1e-9)
//   out    = attn @ Wv (Wv[hm,e] = sum_d W_mv[m,d]*W_out[h*128+d,e]) + bv
// B=32 N=1024 E=512 H=16 M=16 HM=256 ROWS=32768
// Round 10: gemm_a rebuilt as m97-clone — global_load_lds staging (A fp32
// XOR-swizzled via pre-swizzled source, B [kg][col] cells), 2-barrier K-loop,
// 4 blocks/CU co-resident for cross-block drain hiding. gemm_b unchanged.
// ---------------------------------------------------------------------------

typedef unsigned short u16;
typedef unsigned int u32;
typedef short s16x8 __attribute__((ext_vector_type(8)));
typedef float f32x4 __attribute__((ext_vector_type(4)));

// workspace layout (bytes)
constexpr size_t OFF_WKT  = 1u << 20;                 // u16 [256][512]  (256 KiB)
constexpr size_t OFF_WVT  = OFF_WKT + (1u << 18);     // u16 [512][256]  (256 KiB)
constexpr size_t OFF_BK   = OFF_WVT + (1u << 18);     // f32 [256]
constexpr size_t OFF_BV   = OFF_BK + 4096;            // f32 [512]
constexpr size_t OFF_INV  = OFF_BV + 4096;            // f32 [32][256]
constexpr size_t OFF_CP   = 2u << 20;                 // f32 [256][256] colsum partials
constexpr size_t OFF_LOG  = 4u << 20;                 // u16 [32768][256] (16 MiB)
constexpr size_t OFF_WVP  = 40u << 20;                // f32 [128][512][16] (4 MiB)
constexpr size_t OFF_BVP  = 45u << 20;                // f32 [128][512] (256 KiB)

__device__ __forceinline__ float bf2f(u16 v) {
  union { u32 u; float f; } c; c.u = ((u32)v) << 16; return c.f;
}
__device__ __forceinline__ u16 f2bf(float f) {
  union { float f; u32 u; } c; c.f = f;
  u32 u = c.u;
  u += 0x7fffu + ((u >> 16) & 1u);
  return (u16)(u >> 16);
}
// packed RNE f32x2 -> bf16x2 (single HW op; no builtin on gfx950)
__device__ __forceinline__ u32 cvt2(float lo, float hi) {
  u32 r;
  asm("v_cvt_pk_bf16_f32 %0, %1, %2" : "=v"(r) : "v"(lo), "v"(hi));
  return r;
}
__device__ __forceinline__ uint4 pack_bf8(float4 lo, float4 hi) {
  return make_uint4(cvt2(lo.x, lo.y), cvt2(lo.z, lo.w),
                    cvt2(hi.x, hi.y), cvt2(hi.z, hi.w));
}
__device__ __forceinline__ s16x8 as_s16x8(uint4 v) {
  union { uint4 u; s16x8 s; } c; c.u = v; return c.s;
}

__device__ __forceinline__ void mfma_bf16(f32x4& acc, s16x8 a, s16x8 b) {
  asm volatile("v_mfma_f32_16x16x32_bf16 %0, %1, %2, %0"
               : "+v"(acc) : "v"(a), "v"(b));
}

// async global -> LDS, 16 B per lane (global_load_lds_dwordx4)
__device__ __forceinline__ void gl16(const void* g, void* l) {
  __builtin_amdgcn_global_load_lds(
      (const __attribute__((address_space(1))) void*)g,
      (__attribute__((address_space(3))) void*)l, 16, 0, 0);
}

// ---------------------------------------------------------------------------
// WkT[hm][e] = sum_d W_in[e, h*128+d] * W_mk[d, m]   (stored transposed, bf16)
__global__ void prep_wkt(const float* __restrict__ wi, const float* __restrict__ wm,
                         u16* __restrict__ wkT) {
  const int gid = blockIdx.x * 256 + threadIdx.x;
  const int hm = gid & 255, e = gid >> 8;
  const int h = hm >> 4, m = hm & 15;
  float acc = 0.f;
  for (int d = 0; d < 128; d++)
    acc += wi[e * 2048 + h * 128 + d] * wm[d * 16 + m];
  wkT[hm * 512 + e] = f2bf(acc);
}

// wvt partial: block = (h, dc); 16 d's per chunk; coalesced W_out rows.
__global__ __launch_bounds__(256) void wvt_part(const float* __restrict__ mv,
                                                const float* __restrict__ b_mv,
                                                const float* __restrict__ wo,
                                                float* __restrict__ wvp,
                                                float* __restrict__ bvp) {
  __shared__ float wmv_l[16][16];
  __shared__ float bmv_l[16];
  const int blk = blockIdx.x;        // 0..127
  const int h = blk >> 3, dc = blk & 7;
  const int t = threadIdx.x;         // 256
  {
    const int m = t >> 4, dd = t & 15;
    wmv_l[m][dd] = mv[m * 128 + dc * 16 + dd];
    if (t < 16) bmv_l[t] = b_mv[dc * 16 + t];
  }
  __syncthreads();
  float acc0[16], acc1[16];
  float bv0 = 0.f, bv1 = 0.f;
#pragma unroll
  for (int m = 0; m < 16; m++) { acc0[m] = 0.f; acc1[m] = 0.f; }
#pragma unroll
  for (int dd = 0; dd < 16; dd++) {
    const float w0 = wo[(size_t)(h * 128 + dc * 16 + dd) * 512 + t];
    const float w1 = wo[(size_t)(h * 128 + dc * 16 + dd) * 512 + 256 + t];
#pragma unroll
    for (int m = 0; m < 16; m++) {
      const float c = wmv_l[m][dd];
      acc0[m] += c * w0;
      acc1[m] += c * w1;
    }
    bv0 += bmv_l[dd] * w0;
    bv1 += bmv_l[dd] * w1;
  }
  float* w0p = wvp + ((size_t)blk * 512 + t) * 16;
  float* w1p = wvp + ((size_t)blk * 512 + 256 + t) * 16;
#pragma unroll
  for (int m = 0; m < 16; m++) { w0p[m] = acc0[m]; w1p[m] = acc1[m]; }
  bvp[(size_t)blk * 512 + t] = bv0;
  bvp[(size_t)blk * 512 + 256 + t] = bv1;
}

// wvT[e][hm] = f2bf(sum_dc wvp); bv[e] = b_out[e] + sum_blk bvp
__global__ __launch_bounds__(256) void wvt_fin(const float* __restrict__ wvp,
                                               const float* __restrict__ bvp,
                                               const float* __restrict__ b_out,
                                               u16* __restrict__ wvT,
                                               float* __restrict__ bv) {
  const int e = blockIdx.x;   // 512
  const int t = threadIdx.x;  // 256 = hm
  const int h = t >> 4, m = t & 15;
  float s = 0.f;
#pragma unroll
  for (int dc = 0; dc < 8; dc++)
    s += wvp[((size_t)(h * 8 + dc) * 512 + e) * 16 + m];
  wvT[(size_t)e * 256 + t] = f2bf(s);
  if (t < 64) {
    float b = bvp[(size_t)t * 512 + e] + bvp[(size_t)(t + 64) * 512 + e];
#pragma unroll
    for (int mask = 32; mask >= 1; mask >>= 1) b += __shfl_xor(b, mask);
    if (t == 0) bv[e] = b_out[e] + b;
  }
}

// bk[hm] = b_mk[m] + sum_d b_in[h*128+d]*W_mk[d,m]
__global__ void prep_bk(const float* __restrict__ b_in, const float* __restrict__ wm,
                        const float* __restrict__ b_mk, float* __restrict__ bk) {
  const int t = threadIdx.x;
  const int h = t >> 4, m = t & 15;
  float acc = b_mk[m];
  for (int d = 0; d < 128; d++) acc += b_in[h * 128 + d] * wm[d * 16 + m];
  bk[t] = acc;
}

// ---------------------------------------------------------------------------
// GEMM A (m97-clone): logits[32768,256] = x @ Wk + bk (bf16) + colsum.
// Grid (2 colblk, 256 rowblk); 128x128 tile, BK=32, 256 threads (4 waves 2x2,
// wave = 64x64, acc[4][4]).
// A: fp32 in LDS, 16 KiB/step, G4 XOR swizzle (byte^=(row&7)<<4 within the
//    128B row) applied by PRE-SWIZZLING the global source; LDS dest linear.
// B: bf16 cells [kg 0..3][col 0..127] of 16 B, linear (conflict-free reads).
// K-loop: barrier; global_load_lds stage; barrier(drains vmcnt); compute.
// Drain hidden by 4 blocks/CU co-residency (all 512 blocks resident).
__global__ __launch_bounds__(256, 4) void gemm_a(const float* __restrict__ x,
                                                 const u16* __restrict__ wkT,
                                                 const float* __restrict__ bk,
                                                 u16* __restrict__ logits,
                                                 float* __restrict__ cpart) {
  __shared__ float Asf[4096];   // 16 KiB: 128 rows x 128 B (swizzled)
  __shared__ u16 Bs[4096];      //  8 KiB: 4 kg x 128 col x 8 bf16
  __shared__ float cs[2][128];  //  1 KiB: colsum cross-wave
  const int t = threadIdx.x;
  const int l = t & 63, w = t >> 6;
  const int wr = w >> 1, wc = w & 1;
  const int lrow = l & 15, lkg = l >> 4;
  const int gCol0 = blockIdx.x << 7;
  const int gRow0 = blockIdx.y << 7;

  // staging sources (per-thread, pre-swizzled for A)
  const char* xb = (const char*)x;
  const char* wb = (const char*)wkT;
  const char* gA[4]; char* lA[4];
  const char* gB[2]; char* lB[2];
#pragma unroll
  for (int p = 0; p < 4; p++) {
    const int o = p * 4096 + t * 16;          // phys LDS byte
    const int row = o >> 7, inner = o & 127;
    const int linner = inner ^ ((row & 7) << 4);  // logical byte in row
    gA[p] = xb + (size_t)(gRow0 + row) * 2048 + linner;
    lA[p] = (char*)Asf + o;
  }
#pragma unroll
  for (int p = 0; p < 2; p++) {
    const int c = p * 256 + t;                // cell = kg*128 + col
    const int kg = c >> 7, col = c & 127;
    gB[p] = wb + (size_t)(gCol0 + col) * 1024 + kg * 16;
    lB[p] = (char*)Bs + c * 16;
  }

  f32x4 acc[4][4];
#pragma unroll
  for (int i = 0; i < 4; i++)
#pragma unroll
    for (int n = 0; n < 4; n++) acc[i][n] = f32x4{0.f, 0.f, 0.f, 0.f};

  for (int kc = 0; kc < 16; ++kc) {
    __syncthreads();  // all reads of previous step's tiles complete
#pragma unroll
    for (int p = 0; p < 4; p++) gl16(gA[p] + kc * 128, lA[p]);
#pragma unroll
    for (int p = 0; p < 2; p++) gl16(gB[p] + kc * 64, lB[p]);
    __syncthreads();  // implicit vmcnt(0) drain -> tiles visible

    s16x8 af[4];
#pragma unroll
    for (int i = 0; i < 4; i++) {
      const int r = wr * 64 + i * 16 + lrow;
      const int iw0 = (lkg << 5) ^ ((r & 7) << 4);  // swizzled inner byte
      const float4 a0 = *(const float4*)&Asf[r * 32 + (iw0 >> 2)];
      const float4 a1 = *(const float4*)&Asf[r * 32 + ((iw0 ^ 16) >> 2)];
      af[i] = as_s16x8(pack_bf8(a0, a1));
    }
#pragma unroll
    for (int n = 0; n < 4; n++) {
      const s16x8 bfr =
          *(const s16x8*)&Bs[(lkg * 128 + wc * 64 + n * 16 + lrow) * 8];
#pragma unroll
      for (int i = 0; i < 4; i++) mfma_bf16(acc[i][n], af[i], bfr);
    }
  }

  asm volatile("s_nop 7\n\ts_nop 7");
  const int crow = lkg * 4;  // C/D: row = (l>>4)*4 + j, col = l&15
  float esum[4];
#pragma unroll
  for (int n = 0; n < 4; n++) {
    const int col = gCol0 + wc * 64 + n * 16 + lrow;
    const float bias = bk[col];
    float es = 0.f;
#pragma unroll
    for (int i = 0; i < 4; i++) {
      const int row0 = gRow0 + wr * 64 + i * 16 + crow;
#pragma unroll
      for (int j = 0; j < 4; j++) {
        const u16 q = f2bf(acc[i][n][j] + bias);
        logits[(size_t)(row0 + j) * 256 + col] = q;
        es += __expf(bf2f(q));
      }
    }
    esum[n] = es;
  }
#pragma unroll
  for (int n = 0; n < 4; n++) {
    esum[n] += __shfl_xor(esum[n], 16);
    esum[n] += __shfl_xor(esum[n], 32);
  }
  if (l < 16) {
#pragma unroll
    for (int n = 0; n < 4; n++) cs[wr][wc * 64 + n * 16 + l] = esum[n];
  }
  __syncthreads();
  if (t < 128)
    cpart[(size_t)blockIdx.y * 256 + gCol0 + t] = cs[0][t] + cs[1][t];
}

// inv[b][hm] = 1 / sum over the batch's 8 row-block partials
__global__ void colsum_fin(const float* __restrict__ cpart, float* __restrict__ inv) {
  const int b = blockIdx.x, hm = threadIdx.x;
  float s = 0.f;
#pragma unroll
  for (int k = 0; k < 8; k++) s += cpart[(size_t)(b * 8 + k) * 256 + hm];
  inv[b * 256 + hm] = 1.0f / s;
}

// ---------------------------------------------------------------------------
// GEMM B: out[32768,512] = P @ Wv + bv (fp32 out).  (unchanged from round 9)
// Grid (2 colblk, 512 rowblk); block = 64 rows x 256 cols, 8 waves.
// Phase 1 (cooperative): P[64][256] -> 32 KiB swizzled LDS (softmax once).
// Phase 2: barrier-free MFMA loop; A from LDS, B (wvT, L2) depth-2 prefetch.
__global__ __launch_bounds__(512, 4) void gemm_b(const u16* __restrict__ lg,
                                                 const float* __restrict__ inv,
                                                 const u16* __restrict__ wvT,
                                                 const float* __restrict__ bvv,
                                                 float* __restrict__ out) {
  __shared__ u16 Ps[16384];  // 64 rows * 32 kg * 8 bf16 = 32 KiB
  const int t = threadIdx.x;
  const int l = t & 63, w = t >> 6;
  const int lrow = l & 15, lkg = l >> 4;
  const int gCol0 = blockIdx.x << 8;
  const int gRow0 = blockIdx.y << 6;
  const int bIdx = blockIdx.y >> 4;   // 16 row-blocks per batch

  // ---- phase 1: P tile ----
  {
    const int r = t >> 3, ko = t & 7;
    const u16* src = lg + (size_t)(gRow0 + r) * 256 + ko * 32;
    const float* ivp = inv + bIdx * 256 + ko * 32;
    uint4 q[4];
    q[0] = ((const uint4*)src)[0];
    q[1] = ((const uint4*)src)[1];
    q[2] = ((const uint4*)src)[2];
    q[3] = ((const uint4*)src)[3];
    float4 iva[8];
#pragma unroll
    for (int c = 0; c < 8; c++) iva[c] = ((const float4*)ivp)[c];
    float e[32];
#pragma unroll
    for (int c = 0; c < 4; c++) {
      const u32 w0 = q[c].x, w1 = q[c].y, w2 = q[c].z, w3 = q[c].w;
      const float4 ia = iva[c * 2], ib = iva[c * 2 + 1];
      e[c * 8 + 0] = __expf(bf2f((u16)(w0 & 0xffffu))) * ia.x;
      e[c * 8 + 1] = __expf(bf2f((u16)(w0 >> 16)))     * ia.y;
      e[c * 8 + 2] = __expf(bf2f((u16)(w1 & 0xffffu))) * ia.z;
      e[c * 8 + 3] = __expf(bf2f((u16)(w1 >> 16)))     * ia.w;
      e[c * 8 + 4] = __expf(bf2f((u16)(w2 & 0xffffu))) * ib.x;
      e[c * 8 + 5] = __expf(bf2f((u16)(w2 >> 16)))     * ib.y;
      e[c * 8 + 6] = __expf(bf2f((u16)(w3 & 0xffffu))) * ib.z;
      e[c * 8 + 7] = __expf(bf2f((u16)(w3 >> 16)))     * ib.w;
    }
    float s0 = 0.f, s1 = 0.f;
#pragma unroll
    for (int p = 0; p < 16; p++) { s0 += e[p]; s1 += e[16 + p]; }
    const float r0 = 1.0f / (s0 + 1e-9f), r1 = 1.0f / (s1 + 1e-9f);
#pragma unroll
    for (int c = 0; c < 4; c++) {
      const float rs = (c < 2) ? r0 : r1;
      const uint4 cell = make_uint4(
          cvt2(e[c * 8 + 0] * rs, e[c * 8 + 1] * rs),
          cvt2(e[c * 8 + 2] * rs, e[c * 8 + 3] * rs),
          cvt2(e[c * 8 + 4] * rs, e[c * 8 + 5] * rs),
          cvt2(e[c * 8 + 6] * rs, e[c * 8 + 7] * rs));
      const int kg = ko * 4 + c;
      *(uint4*)&Ps[((r << 5) + (kg ^ (r & 7))) * 8] = cell;
    }
  }
  __syncthreads();

  // ---- phase 2: GEMM ----
  f32x4 acc[4][2];
#pragma unroll
  for (int i = 0; i < 4; i++)
#pragma unroll
    for (int n = 0; n < 2; n++) acc[i][n] = f32x4{0.f, 0.f, 0.f, 0.f};

  const u16* bBase = wvT + (size_t)(gCol0 + w * 32 + lrow) * 256 + lkg * 8;
  uint4 bPre[2][2];
  bPre[0][0] = *(const uint4*)(bBase);
  bPre[0][1] = *(const uint4*)(bBase + 16 * 256);
  bPre[1][0] = *(const uint4*)(bBase + 32);
  bPre[1][1] = *(const uint4*)(bBase + 16 * 256 + 32);

#pragma unroll
  for (int kc = 0; kc < 8; ++kc) {
    const int d = kc & 1;
    s16x8 af[4];
#pragma unroll
    for (int i = 0; i < 4; i++)
      af[i] = *(const s16x8*)
          &Ps[(((i * 16 + lrow) << 5) + ((kc * 4 + lkg) ^ (lrow & 7))) * 8];
    const s16x8 b0 = as_s16x8(bPre[d][0]);
    const s16x8 b1 = as_s16x8(bPre[d][1]);
    if (kc + 2 < 8) {
      bPre[d][0] = *(const uint4*)(bBase + (kc + 2) * 32);
      bPre[d][1] = *(const uint4*)(bBase + 16 * 256 + (kc + 2) * 32);
    }
#pragma unroll
    for (int i = 0; i < 4; i++) {
      mfma_bf16(acc[i][0], af[i], b0);
      mfma_bf16(acc[i][1], af[i], b1);
    }
  }

  asm volatile("s_nop 7\n\ts_nop 7");
  const int crow = lkg * 4;
#pragma unroll
  for (int n = 0; n < 2; n++) {
    const int col = gCol0 + w * 32 + n * 16 + lrow;
    const float bias = bvv[col];
#pragma unroll
    for (int i = 0; i < 4; i++) {
      const int row0 = gRow0 + i * 16 + crow;
#pragma unroll
      for (int j = 0; j < 4; j++)
        out[(size_t)(row0 + j) * 512 + col] = acc[i][n][j] + bias;
    }
  }
}

// ---------------------------------------------------------------------------
extern "C" void kernel_launch(void* const* d_in, const int* in_sizes, int n_in,
                              void* d_out, int out_size, void* d_ws, size_t ws_size,
                              hipStream_t stream) {
  (void)in_sizes; (void)n_in; (void)out_size; (void)ws_size;
  const float* x     = (const float*)d_in[0];
  const float* W_in  = (const float*)d_in[1];
  const float* b_in  = (const float*)d_in[2];
  const float* W_mk  = (const float*)d_in[3];
  const float* b_mk  = (const float*)d_in[4];
  const float* W_mv  = (const float*)d_in[5];
  const float* b_mv  = (const float*)d_in[6];
  const float* W_out = (const float*)d_in[7];
  const float* b_out = (const float*)d_in[8];

  char* ws = (char*)d_ws;
  u16*   wkT  = (u16*)(ws + OFF_WKT);
  u16*   wvT  = (u16*)(ws + OFF_WVT);
  float* bk   = (float*)(ws + OFF_BK);
  float* bv   = (float*)(ws + OFF_BV);
  float* inv  = (float*)(ws + OFF_INV);
  float* cp   = (float*)(ws + OFF_CP);
  u16*   lg   = (u16*)(ws + OFF_LOG);
  float* wvp  = (float*)(ws + OFF_WVP);
  float* bvp  = (float*)(ws + OFF_BVP);
  float* outp = (float*)d_out;

  prep_wkt<<<512, 256, 0, stream>>>(W_in, W_mk, wkT);
  wvt_part<<<128, 256, 0, stream>>>(W_mv, b_mv, W_out, wvp, bvp);
  wvt_fin<<<512, 256, 0, stream>>>(wvp, bvp, b_out, wvT, bv);
  prep_bk<<<1, 256, 0, stream>>>(b_in, W_mk, b_mk, bk);
  gemm_a<<<dim3(2, 256), 256, 0, stream>>>(x, wkT, bk, lg, cp);
  colsum_fin<<<32, 256, 0, stream>>>(cp, inv);
  gemm_b<<<dim3(2, 512), 512, 0, stream>>>(lg, inv, wvT, bv, outp);
}